// Round 1
// baseline (182.530 us; speedup 1.0000x reference)
//
#include <hip/hip_runtime.h>
#include <hip/hip_bf16.h>

// Problem constants (from reference): b=2,h=8 -> BH=16; t=s=384; d=64.
#define BH 16
#define NT 384
#define NS 384
#define DD 64

static constexpr float TWO_LOG2E = 2.8853900817779268f; // 2*log2(e)
static constexpr float LOG2E     = 1.4426950408889634f;

// Static scratch: Ea = exp(2*qp), Eb = exp(2*kp). 2 x 1.5 MB.
__device__ float g_Ea[(size_t)BH * NT * DD];
__device__ float g_Eb[(size_t)BH * NS * DD];

// ---------------------------------------------------------------------------
// K1: qp = q @ Wq^T, kp = k @ Wk^T, then E = exp(2*proj) = exp2(2*log2e*proj)
// One wave handles 16 rows; lane <-> output feature e. W row hoisted to VGPRs,
// x row is wave-uniform (scalar loads). 768 waves total (2 tensors).
// ---------------------------------------------------------------------------
__global__ __launch_bounds__(256) void k1_proj(
    const float* __restrict__ q, const float* __restrict__ k,
    const float* __restrict__ Wq, const float* __restrict__ Wk)
{
    const int wid  = blockIdx.x * 4 + (threadIdx.x >> 6); // [0, 768)
    const int lane = threadIdx.x & 63;
    const int tensor   = wid / 384;          // 0 = query path, 1 = key path
    const int base_row = (wid % 384) * 16;   // rows in [0, 6144)

    const float* __restrict__ X = tensor ? k  : q;
    const float* __restrict__ W = tensor ? Wk : Wq;
    float* __restrict__ E       = tensor ? g_Eb : g_Ea;

    // lane's W row: W[e=lane][0:64]
    float wr[64];
    const float* wrow = W + lane * 64;
#pragma unroll
    for (int i = 0; i < 64; i += 4) {
        float4 v = *reinterpret_cast<const float4*>(wrow + i);
        wr[i] = v.x; wr[i + 1] = v.y; wr[i + 2] = v.z; wr[i + 3] = v.w;
    }

    for (int r = 0; r < 16; ++r) {
        const size_t row = (size_t)(base_row + r);
        const float* __restrict__ xr = X + row * 64; // wave-uniform address
        float a0 = 0.f, a1 = 0.f, a2 = 0.f, a3 = 0.f;
#pragma unroll
        for (int d = 0; d < 64; d += 4) {
            a0 = fmaf(xr[d + 0], wr[d + 0], a0);
            a1 = fmaf(xr[d + 1], wr[d + 1], a1);
            a2 = fmaf(xr[d + 2], wr[d + 2], a2);
            a3 = fmaf(xr[d + 3], wr[d + 3], a3);
        }
        const float dot = (a0 + a1) + (a2 + a3);
        E[row * 64 + lane] = __builtin_amdgcn_exp2f(TWO_LOG2E * dot);
    }
}

// ---------------------------------------------------------------------------
// K2: raw scores. score[t,s] = C0 - 2 * sum_e vw[e] * rcp(1 + Ea[t,e]*Eb[s,e])
// Wave owns (bh, s-chunk of 64 via lanes, 16 t rows). Eb row hoisted into 64
// VGPRs per lane; Ea/vw wave-uniform. Pure fma+rcp inner loop, 4 accumulators.
// Writes raw scores into the attention region of d_out (softmaxed by K3).
// ---------------------------------------------------------------------------
__global__ __launch_bounds__(256) void k2_scores(
    const float* __restrict__ v_w, float* __restrict__ attn)
{
    const int wid  = blockIdx.x * 4 + (threadIdx.x >> 6); // [0, 2304)
    const int lane = threadIdx.x & 63;
    const int bh  = wid / 144;         // 144 = 6 s-chunks * 24 t-chunks
    const int rem = wid % 144;
    const int sc  = rem / 24;          // s-chunk [0,6)
    const int t0  = (rem % 24) * 16;   // 16 t rows per wave

    // lane's Eb row: Eb[s = sc*64+lane][0:64]
    float eb[64];
    const float* ebp = g_Eb + ((size_t)(bh * NS + sc * 64 + lane)) * 64;
#pragma unroll
    for (int i = 0; i < 64; i += 4) {
        float4 v = *reinterpret_cast<const float4*>(ebp + i);
        eb[i] = v.x; eb[i + 1] = v.y; eb[i + 2] = v.z; eb[i + 3] = v.w;
    }

    // v_w (wave-uniform)
    float vv[64];
#pragma unroll
    for (int i = 0; i < 64; i += 4) {
        float4 v = *reinterpret_cast<const float4*>(v_w + i);
        vv[i] = v.x; vv[i + 1] = v.y; vv[i + 2] = v.z; vv[i + 3] = v.w;
    }
    float C0 = 0.f;
#pragma unroll
    for (int i = 0; i < 64; ++i) C0 += vv[i];

    for (int tt = 0; tt < 16; ++tt) {
        const int t = t0 + tt;
        const float* __restrict__ ear = g_Ea + ((size_t)(bh * NT + t)) * 64; // uniform
        float a0 = 0.f, a1 = 0.f, a2 = 0.f, a3 = 0.f;
#pragma unroll
        for (int e = 0; e < 64; e += 4) {
            const float d0 = fmaf(ear[e + 0], eb[e + 0], 1.0f);
            const float d1 = fmaf(ear[e + 1], eb[e + 1], 1.0f);
            const float d2 = fmaf(ear[e + 2], eb[e + 2], 1.0f);
            const float d3 = fmaf(ear[e + 3], eb[e + 3], 1.0f);
            a0 = fmaf(vv[e + 0], __builtin_amdgcn_rcpf(d0), a0);
            a1 = fmaf(vv[e + 1], __builtin_amdgcn_rcpf(d1), a1);
            a2 = fmaf(vv[e + 2], __builtin_amdgcn_rcpf(d2), a2);
            a3 = fmaf(vv[e + 3], __builtin_amdgcn_rcpf(d3), a3);
        }
        const float score = C0 - 2.0f * ((a0 + a1) + (a2 + a3));
        attn[((size_t)(bh * NT + t)) * NS + sc * 64 + lane] = score;
    }
}

// ---------------------------------------------------------------------------
// K3: in-place softmax over s (384) per row. Wave per row, 8 rows per wave.
// lane holds 6 values (s = lane + 64*i); butterfly shfl_xor reductions.
// ---------------------------------------------------------------------------
__global__ __launch_bounds__(256) void k3_softmax(float* __restrict__ attn)
{
    const int wid  = blockIdx.x * 4 + (threadIdx.x >> 6); // [0, 768)
    const int lane = threadIdx.x & 63;

    for (int j = 0; j < 8; ++j) {
        const size_t row = (size_t)wid * 8 + j; // [0, 6144)
        float* __restrict__ sr = attn + row * NS;
        float v0 = sr[lane];
        float v1 = sr[lane + 64];
        float v2 = sr[lane + 128];
        float v3 = sr[lane + 192];
        float v4 = sr[lane + 256];
        float v5 = sr[lane + 320];
        float m = fmaxf(fmaxf(fmaxf(v0, v1), fmaxf(v2, v3)), fmaxf(v4, v5));
#pragma unroll
        for (int o = 32; o > 0; o >>= 1) m = fmaxf(m, __shfl_xor(m, o, 64));
        const float p0 = __builtin_amdgcn_exp2f((v0 - m) * LOG2E);
        const float p1 = __builtin_amdgcn_exp2f((v1 - m) * LOG2E);
        const float p2 = __builtin_amdgcn_exp2f((v2 - m) * LOG2E);
        const float p3 = __builtin_amdgcn_exp2f((v3 - m) * LOG2E);
        const float p4 = __builtin_amdgcn_exp2f((v4 - m) * LOG2E);
        const float p5 = __builtin_amdgcn_exp2f((v5 - m) * LOG2E);
        float s = ((p0 + p1) + (p2 + p3)) + (p4 + p5);
#pragma unroll
        for (int o = 32; o > 0; o >>= 1) s += __shfl_xor(s, o, 64);
        const float inv = __builtin_amdgcn_rcpf(s);
        sr[lane]       = p0 * inv;
        sr[lane + 64]  = p1 * inv;
        sr[lane + 128] = p2 * inv;
        sr[lane + 192] = p3 * inv;
        sr[lane + 256] = p4 * inv;
        sr[lane + 320] = p5 * inv;
    }
}

// ---------------------------------------------------------------------------
// K4: out[t,d] = sum_s attn[t,s] * V[s,d]. Wave owns (bh, 8 t rows), lane<->d.
// V chunk (64 s rows) hoisted into 64 VGPRs; attn row wave-uniform -> pure
// v_fmac inner loop. Accumulates across all 6 s-chunks in registers.
// ---------------------------------------------------------------------------
__global__ __launch_bounds__(256) void k4_pv(
    const float* __restrict__ attn, const float* __restrict__ V,
    float* __restrict__ out)
{
    const int wid  = blockIdx.x * 4 + (threadIdx.x >> 6); // [0, 768)
    const int lane = threadIdx.x & 63;
    const int bh = wid / 48;
    const int t0 = (wid % 48) * 8;

    float acc[8] = {0.f, 0.f, 0.f, 0.f, 0.f, 0.f, 0.f, 0.f};

    for (int sc = 0; sc < 6; ++sc) {
        // V[s = sc*64 + i][d = lane], i = 0..63, into registers
        float vr[64];
        const float* vp = V + ((size_t)(bh * NS + sc * 64)) * 64 + lane;
#pragma unroll
        for (int i = 0; i < 64; ++i) vr[i] = vp[(size_t)i * 64];

#pragma unroll
        for (int tt = 0; tt < 8; ++tt) {
            const float* __restrict__ ar =
                attn + ((size_t)(bh * NT + t0 + tt)) * NS + sc * 64; // uniform
            float p0 = 0.f, p1 = 0.f, p2 = 0.f, p3 = 0.f;
#pragma unroll
            for (int i = 0; i < 64; i += 4) {
                p0 = fmaf(ar[i + 0], vr[i + 0], p0);
                p1 = fmaf(ar[i + 1], vr[i + 1], p1);
                p2 = fmaf(ar[i + 2], vr[i + 2], p2);
                p3 = fmaf(ar[i + 3], vr[i + 3], p3);
            }
            acc[tt] += (p0 + p1) + (p2 + p3);
        }
    }
#pragma unroll
    for (int tt = 0; tt < 8; ++tt)
        out[((size_t)(bh * NT + t0 + tt)) * 64 + lane] = acc[tt];
}

extern "C" void kernel_launch(void* const* d_in, const int* in_sizes, int n_in,
                              void* d_out, int out_size, void* d_ws, size_t ws_size,
                              hipStream_t stream) {
    const float* q  = (const float*)d_in[0];
    const float* k  = (const float*)d_in[1];
    const float* v  = (const float*)d_in[2];
    const float* Wq = (const float*)d_in[3];
    const float* Wk = (const float*)d_in[4];
    const float* vw = (const float*)d_in[5];

    float* out  = (float*)d_out;                      // (b,h,t,d) = 393216
    float* attn = out + (size_t)BH * NT * DD;         // (b,h,t,s) = 2359296

    k1_proj   <<<192, 256, 0, stream>>>(q, k, Wq, Wk);
    k2_scores <<<576, 256, 0, stream>>>(vw, attn);
    k3_softmax<<<192, 256, 0, stream>>>(attn);
    k4_pv     <<<192, 256, 0, stream>>>(attn, v, out);
}

// Round 5
// 118.808 us; speedup vs baseline: 1.5363x; 1.5363x over previous
//
#include <hip/hip_runtime.h>
#include <hip/hip_bf16.h>

// Problem constants (from reference): b=2,h=8 -> BH=16; t=s=384; d=64.
#define BH 16
#define NT 384
#define NS 384
#define DD 64

static constexpr float TWO_LOG2E = 2.8853900817779268f; // 2*log2(e)
static constexpr float LOG2E     = 1.4426950408889634f;

// Static scratch: Ea = exp(2*qp), Eb = exp(2*kp). 2 x 1.5 MB. 16B aligned.
__device__ float4 g_Ea4[(size_t)BH * NT * DD / 4];
__device__ float4 g_Eb4[(size_t)BH * NS * DD / 4];
// PV partials (s-split into 2 halves): 2 x 1.5 MB.
__device__ float4 g_part4[2 * (size_t)BH * NT * DD / 4];

// ---------------------------------------------------------------------------
// K1: proj + exp. Block owns 32 rows of one tensor (q or k). x-tile staged in
// LDS (coalesced flat copy); W row per lane in VGPRs; x read back as uniform
// LDS b128 broadcasts. Grid 384, 1536 waves.
// ---------------------------------------------------------------------------
__global__ __launch_bounds__(256) void k1_proj(
    const float* __restrict__ q, const float* __restrict__ k,
    const float* __restrict__ Wq, const float* __restrict__ Wk)
{
    __shared__ float xt[32 * 64]; // 8KB
    const int bid    = blockIdx.x;       // [0, 384)
    const int tensor = bid / 192;        // 0=q, 1=k
    const int tile   = bid % 192;        // 32-row tiles over 6144 rows
    const int tid  = threadIdx.x;
    const int lane = tid & 63;
    const int w    = tid >> 6;

    const float* __restrict__ X = tensor ? k  : q;
    const float* __restrict__ W = tensor ? Wk : Wq;
    float* __restrict__ E = tensor ? (float*)g_Eb4 : (float*)g_Ea4;

    const size_t base = (size_t)tile * 32;

    // stage x tile: 2048 floats, flat coalesced
    {
        const float4* __restrict__ src =
            reinterpret_cast<const float4*>(X + base * 64);
        float4* dst = reinterpret_cast<float4*>(xt);
#pragma unroll
        for (int i = 0; i < 2; ++i) dst[tid + i * 256] = src[tid + i * 256];
    }

    // lane's W row: W[e=lane][0:64]
    float wr[64];
    {
        const float* wrow = W + lane * 64;
#pragma unroll
        for (int i = 0; i < 64; i += 4) {
            float4 v = *reinterpret_cast<const float4*>(wrow + i);
            wr[i] = v.x; wr[i + 1] = v.y; wr[i + 2] = v.z; wr[i + 3] = v.w;
        }
    }
    __syncthreads();

#pragma unroll
    for (int r8 = 0; r8 < 8; ++r8) {
        const int r = w * 8 + r8; // [0,32)
        float a0 = 0.f, a1 = 0.f, a2 = 0.f, a3 = 0.f;
#pragma unroll
        for (int d4 = 0; d4 < 16; ++d4) {
            const float4 xv = *reinterpret_cast<const float4*>(&xt[r * 64 + d4 * 4]);
            a0 = fmaf(xv.x, wr[d4 * 4 + 0], a0);
            a1 = fmaf(xv.y, wr[d4 * 4 + 1], a1);
            a2 = fmaf(xv.z, wr[d4 * 4 + 2], a2);
            a3 = fmaf(xv.w, wr[d4 * 4 + 3], a3);
        }
        const float dot = (a0 + a1) + (a2 + a3);
        E[(base + r) * 64 + lane] = __builtin_amdgcn_exp2f(TWO_LOG2E * dot);
    }
}

// ---------------------------------------------------------------------------
// K2: raw scores. score[t,s] = C0 - 2 * sum_e vw[e] * rcp(1 + Ea[t,e]*Eb[s,e])
// Block owns (bh, 32-t tile, 64-s chunk). Ea tile + Eb chunk staged in LDS
// (coalesced); eb hoisted to 64 VGPRs per lane; Ea read as uniform b128
// broadcasts. Grid 1152 (16*12*6), 4608 waves.
// ---------------------------------------------------------------------------
__global__ __launch_bounds__(256) void k2_scores(
    const float* __restrict__ v_w, float* __restrict__ attn)
{
    __shared__ float ea[32 * 64];  // 8KB
    __shared__ float ebl[64 * 68]; // padded, 17KB
    const int bid = blockIdx.x;    // [0, 1152)
    const int bh  = bid / 72;
    const int rem = bid % 72;
    const int tt  = rem / 6;       // t-tile [0,12), 32 rows each
    const int sc  = rem % 6;       // s-chunk [0,6)
    const int tid  = threadIdx.x;
    const int lane = tid & 63;
    const int w    = tid >> 6;

    const float* Ea = (const float*)g_Ea4;
    const float* Eb = (const float*)g_Eb4;

    // stage Ea tile: 2048 floats flat coalesced
    {
        const float4* __restrict__ src =
            reinterpret_cast<const float4*>(Ea + ((size_t)bh * NT + tt * 32) * 64);
        float4* dst = reinterpret_cast<float4*>(ea);
#pragma unroll
        for (int i = 0; i < 2; ++i) dst[tid + i * 256] = src[tid + i * 256];
    }
    // stage Eb chunk into padded [64][68]
    {
        const float4* __restrict__ src =
            reinterpret_cast<const float4*>(Eb + ((size_t)bh * NS + sc * 64) * 64);
#pragma unroll
        for (int i = 0; i < 4; ++i) {
            const int j   = tid + i * 256; // f4 index [0,1024)
            const int row = j >> 4;
            const int c4  = j & 15;
            *reinterpret_cast<float4*>(&ebl[row * 68 + c4 * 4]) = src[j];
        }
    }

    // v_w (uniform) into regs + C0
    float vv[64];
#pragma unroll
    for (int i = 0; i < 64; i += 4) {
        float4 v = *reinterpret_cast<const float4*>(v_w + i);
        vv[i] = v.x; vv[i + 1] = v.y; vv[i + 2] = v.z; vv[i + 3] = v.w;
    }
    float C0 = 0.f;
#pragma unroll
    for (int i = 0; i < 64; ++i) C0 += vv[i];

    __syncthreads();

    // hoist lane's Eb row from LDS
    float eb[64];
#pragma unroll
    for (int e4 = 0; e4 < 16; ++e4) {
        float4 v = *reinterpret_cast<const float4*>(&ebl[lane * 68 + e4 * 4]);
        eb[e4 * 4 + 0] = v.x; eb[e4 * 4 + 1] = v.y;
        eb[e4 * 4 + 2] = v.z; eb[e4 * 4 + 3] = v.w;
    }

#pragma unroll
    for (int r8 = 0; r8 < 8; ++r8) {
        const int tloc = w * 8 + r8; // [0,32)
        float a0 = 0.f, a1 = 0.f, a2 = 0.f, a3 = 0.f;
#pragma unroll
        for (int e4 = 0; e4 < 16; ++e4) {
            const float4 A = *reinterpret_cast<const float4*>(&ea[tloc * 64 + e4 * 4]);
            const float d0 = fmaf(A.x, eb[e4 * 4 + 0], 1.0f);
            const float d1 = fmaf(A.y, eb[e4 * 4 + 1], 1.0f);
            const float d2 = fmaf(A.z, eb[e4 * 4 + 2], 1.0f);
            const float d3 = fmaf(A.w, eb[e4 * 4 + 3], 1.0f);
            a0 = fmaf(vv[e4 * 4 + 0], __builtin_amdgcn_rcpf(d0), a0);
            a1 = fmaf(vv[e4 * 4 + 1], __builtin_amdgcn_rcpf(d1), a1);
            a2 = fmaf(vv[e4 * 4 + 2], __builtin_amdgcn_rcpf(d2), a2);
            a3 = fmaf(vv[e4 * 4 + 3], __builtin_amdgcn_rcpf(d3), a3);
        }
        const float score = C0 - 2.0f * ((a0 + a1) + (a2 + a3));
        attn[((size_t)bh * NT + tt * 32 + tloc) * NS + sc * 64 + lane] = score;
    }
}

// ---------------------------------------------------------------------------
// K3: in-place softmax over s (384) per row. One wave per row. Grid 1536.
// ---------------------------------------------------------------------------
__global__ __launch_bounds__(256) void k3_softmax(float* __restrict__ attn)
{
    const int row  = blockIdx.x * 4 + (threadIdx.x >> 6); // [0, 6144)
    const int lane = threadIdx.x & 63;

    float* __restrict__ sr = attn + (size_t)row * NS;
    float v0 = sr[lane];
    float v1 = sr[lane + 64];
    float v2 = sr[lane + 128];
    float v3 = sr[lane + 192];
    float v4 = sr[lane + 256];
    float v5 = sr[lane + 320];
    float m = fmaxf(fmaxf(fmaxf(v0, v1), fmaxf(v2, v3)), fmaxf(v4, v5));
#pragma unroll
    for (int o = 32; o > 0; o >>= 1) m = fmaxf(m, __shfl_xor(m, o, 64));
    const float p0 = __builtin_amdgcn_exp2f((v0 - m) * LOG2E);
    const float p1 = __builtin_amdgcn_exp2f((v1 - m) * LOG2E);
    const float p2 = __builtin_amdgcn_exp2f((v2 - m) * LOG2E);
    const float p3 = __builtin_amdgcn_exp2f((v3 - m) * LOG2E);
    const float p4 = __builtin_amdgcn_exp2f((v4 - m) * LOG2E);
    const float p5 = __builtin_amdgcn_exp2f((v5 - m) * LOG2E);
    float s = ((p0 + p1) + (p2 + p3)) + (p4 + p5);
#pragma unroll
    for (int o = 32; o > 0; o >>= 1) s += __shfl_xor(s, o, 64);
    const float inv = __builtin_amdgcn_rcpf(s);
    sr[lane]       = p0 * inv;
    sr[lane + 64]  = p1 * inv;
    sr[lane + 128] = p2 * inv;
    sr[lane + 192] = p3 * inv;
    sr[lane + 256] = p4 * inv;
    sr[lane + 320] = p5 * inv;
}

// ---------------------------------------------------------------------------
// K4: partial PV. Block owns (bh, 16-t tile, s-half). V-chunk + attn-tile
// staged in LDS; V column hoisted into vr[64] (2-way = free); attn read as
// uniform b128. Grid 768 (16*24*2), 3072 waves. Partials to g_part4.
// ---------------------------------------------------------------------------
__global__ __launch_bounds__(256) void k4_pv(
    const float* __restrict__ attn, const float* __restrict__ V)
{
    __shared__ float vt[64 * 64]; // 16KB
    __shared__ float at[16 * 64]; // 4KB
    const int bid = blockIdx.x;   // [0, 768)
    const int bh  = bid / 48;
    const int rem = bid % 48;
    const int tt  = rem / 2;      // 16-row t-tile [0,24)
    const int sh  = rem % 2;      // s half
    const int tid  = threadIdx.x;
    const int lane = tid & 63;
    const int w    = tid >> 6;

    float acc[4] = {0.f, 0.f, 0.f, 0.f};

    for (int sc3 = 0; sc3 < 3; ++sc3) {
        const int sc = sh * 3 + sc3;
        __syncthreads(); // protect LDS from previous iteration's readers
        // stage V chunk: 4096 floats flat coalesced
        {
            const float4* __restrict__ src =
                reinterpret_cast<const float4*>(V + ((size_t)bh * NS + sc * 64) * 64);
            float4* dst = reinterpret_cast<float4*>(vt);
#pragma unroll
            for (int i = 0; i < 4; ++i) dst[tid + i * 256] = src[tid + i * 256];
        }
        // stage attn tile: 16 rows x 64 cols
        {
            const int row = tid >> 4;        // [0,16)
            const int c4  = tid & 15;        // [0,16)
            const float4* __restrict__ src = reinterpret_cast<const float4*>(
                attn + ((size_t)bh * NT + tt * 16 + row) * NS + sc * 64);
            *reinterpret_cast<float4*>(&at[row * 64 + c4 * 4]) = src[c4];
        }
        __syncthreads();

        // hoist V column: vr[i] = V[sc*64+i][lane]
        float vr[64];
#pragma unroll
        for (int i = 0; i < 64; ++i) vr[i] = vt[i * 64 + lane];

#pragma unroll
        for (int t4 = 0; t4 < 4; ++t4) {
            const int tloc = w * 4 + t4; // [0,16)
            float p0 = 0.f, p1 = 0.f, p2 = 0.f, p3 = 0.f;
#pragma unroll
            for (int e4 = 0; e4 < 16; ++e4) {
                const float4 P = *reinterpret_cast<const float4*>(&at[tloc * 64 + e4 * 4]);
                p0 = fmaf(P.x, vr[e4 * 4 + 0], p0);
                p1 = fmaf(P.y, vr[e4 * 4 + 1], p1);
                p2 = fmaf(P.z, vr[e4 * 4 + 2], p2);
                p3 = fmaf(P.w, vr[e4 * 4 + 3], p3);
            }
            acc[t4] += (p0 + p1) + (p2 + p3);
        }
    }

    float* __restrict__ part = (float*)g_part4 + (size_t)sh * BH * NT * DD;
#pragma unroll
    for (int t4 = 0; t4 < 4; ++t4) {
        const int t = tt * 16 + w * 4 + t4;
        part[((size_t)bh * NT + t) * DD + lane] = acc[t4];
    }
}

// ---------------------------------------------------------------------------
// K5: out = part0 + part1 (float4). Grid 384.
// ---------------------------------------------------------------------------
__global__ __launch_bounds__(256) void k5_combine(float4* __restrict__ out4)
{
    const int i = blockIdx.x * 256 + threadIdx.x; // [0, 98304)
    const float4 a = g_part4[i];
    const float4 b = g_part4[i + (size_t)BH * NT * DD / 4];
    float4 r;
    r.x = a.x + b.x; r.y = a.y + b.y; r.z = a.z + b.z; r.w = a.w + b.w;
    out4[i] = r;
}

extern "C" void kernel_launch(void* const* d_in, const int* in_sizes, int n_in,
                              void* d_out, int out_size, void* d_ws, size_t ws_size,
                              hipStream_t stream) {
    const float* q  = (const float*)d_in[0];
    const float* k  = (const float*)d_in[1];
    const float* v  = (const float*)d_in[2];
    const float* Wq = (const float*)d_in[3];
    const float* Wk = (const float*)d_in[4];
    const float* vw = (const float*)d_in[5];

    float* out  = (float*)d_out;              // (b,h,t,d) = 393216
    float* attn = out + (size_t)BH * NT * DD; // (b,h,t,s) = 2359296

    k1_proj   <<<384,  256, 0, stream>>>(q, k, Wq, Wk);
    k2_scores <<<1152, 256, 0, stream>>>(vw, attn);
    k3_softmax<<<1536, 256, 0, stream>>>(attn);
    k4_pv     <<<768,  256, 0, stream>>>(attn, v);
    k5_combine<<<384,  256, 0, stream>>>((float4*)out);
}